// Round 6
// baseline (324.473 us; speedup 1.0000x reference)
//
#include <hip/hip_runtime.h>

#define IN_F 128
#define HID_F 64
#define BKT_SHIFT 9            // 512 nodes per bucket
#define BKT_SIZE 512
#define CHUNK 4096             // edges per block in binning kernels

typedef unsigned short ushort_t;
typedef __attribute__((ext_vector_type(8))) short bf16x8;
typedef __attribute__((ext_vector_type(8))) unsigned short u16x8;
typedef __attribute__((ext_vector_type(4))) float f32x4;

__device__ inline ushort_t f2bf(float f) {     // RNE fp32 -> bf16 bits
    unsigned u = __float_as_uint(f);
    u += 0x7FFFu + ((u >> 16) & 1u);
    return (ushort_t)(u >> 16);
}
__device__ inline float bf2f(ushort_t u) {
    return __uint_as_float((unsigned)u << 16);
}

// ---------------- CSR build: atomic-free 2-level bucket sort by dst ----------------
// pack: (dst & 511) << 23 | src   (needs src < 2^23, nodes/bucket <= 512)

// per-block LDS histogram -> ghist[block][bucket]  (no global atomics)
__global__ __launch_bounds__(256) void k_hist(const int* __restrict__ dst,
        int* __restrict__ ghist, int E) {
    __shared__ int hist[256];
    int tid = threadIdx.x;
    hist[tid] = 0;
    __syncthreads();
    int e0 = blockIdx.x * CHUNK, e1 = min(e0 + CHUNK, E);
    for (int e = e0 + tid; e < e1; e += 256)
        atomicAdd(&hist[dst[e] >> BKT_SHIFT], 1);
    __syncthreads();
    ghist[blockIdx.x * 256 + tid] = hist[tid];
}

// single block: thread t = bucket t. Serial scan over blocks (ghist -> running
// offsets within bucket), then block-wide scan for bucket bases.
__global__ __launch_bounds__(256) void k_scanhist(int* __restrict__ ghist,
        int* __restrict__ gbase, int* __restrict__ bbase, int* __restrict__ rowptr,
        int nb, int N, int E) {
    __shared__ int s[256];
    int t = threadIdx.x;
    int run = 0;
    for (int j = 0; j < nb; ++j) {
        int v = ghist[j * 256 + t];
        ghist[j * 256 + t] = run;
        run += v;
    }
    s[t] = run;
    __syncthreads();
    for (int off = 1; off < 256; off <<= 1) {
        int v = (t >= off) ? s[t - off] : 0;
        __syncthreads();
        s[t] += v;
        __syncthreads();
    }
    int base = s[t] - run;
    gbase[t] = base;
    bbase[t] = base;
    if (t == 255) bbase[256] = s[255];   // == E
    if (t == 0) rowptr[N] = E;
}

// scatter into bucket-contiguous gbin; cursors seeded from table, LDS atomics only
__global__ __launch_bounds__(256) void k_scatter(const int* __restrict__ src,
        const int* __restrict__ dst, const int* __restrict__ ghist,
        const int* __restrict__ gbase, unsigned* __restrict__ gbin, int E) {
    __shared__ int cur[256];
    int tid = threadIdx.x;
    cur[tid] = ghist[blockIdx.x * 256 + tid] + gbase[tid];
    __syncthreads();
    int e0 = blockIdx.x * CHUNK, e1 = min(e0 + CHUNK, E);
    for (int e = e0 + tid; e < e1; e += 256) {
        int d = dst[e];
        int b = d >> BKT_SHIFT;
        int p = atomicAdd(&cur[b], 1);
        gbin[p] = ((unsigned)(d & (BKT_SIZE - 1)) << 23) | (unsigned)src[e];
    }
}

// one block per bucket: per-node count (LDS), LDS scan of 512, write rowptr/dinv
// coalesced, then scatter col within the bucket's hot window via LDS cursors.
__global__ __launch_bounds__(256) void k_fill2(const unsigned* __restrict__ gbin,
        const int* __restrict__ bbase, int* __restrict__ rowptr,
        float* __restrict__ dinv, int* __restrict__ col, int N) {
    __shared__ int cnt[BKT_SIZE];
    __shared__ int pos[BKT_SIZE];
    __shared__ int s[256];
    int tid = threadIdx.x;
    int b = blockIdx.x;
    int e0 = bbase[b], e1 = bbase[b + 1];
    cnt[tid] = 0; cnt[tid + 256] = 0;
    __syncthreads();
    for (int e = e0 + tid; e < e1; e += 256)
        atomicAdd(&cnt[gbin[e] >> 23], 1);
    __syncthreads();
    int c0 = cnt[2 * tid], c1 = cnt[2 * tid + 1];
    int p2 = c0 + c1;
    s[tid] = p2;
    __syncthreads();
    for (int off = 1; off < 256; off <<= 1) {
        int v = (tid >= off) ? s[tid - off] : 0;
        __syncthreads();
        s[tid] += v;
        __syncthreads();
    }
    int excl = s[tid] - p2;
    pos[2 * tid] = excl;
    pos[2 * tid + 1] = excl + c0;
    __syncthreads();
    int n0 = b << BKT_SHIFT;
    #pragma unroll
    for (int i = tid; i < BKT_SIZE; i += 256) {
        int n = n0 + i;
        if (n < N) {
            rowptr[n] = e0 + pos[i];
            dinv[n] = rsqrtf((float)cnt[i] + 1.0f);   // +1 self-loop
        }
    }
    __syncthreads();
    for (int e = e0 + tid; e < e1; e += 256) {
        unsigned v = gbin[e];
        int p = atomicAdd(&pos[v >> 23], 1);
        col[e0 + p] = (int)(v & 0x7FFFFFu);
    }
}

// ---------------- W pre-pack into MFMA B-fragment order (bf16) ----------------
// B-frag (16x16x32): lane holds B[k = (lane>>4)*8 + j][n = lane&15], j=0..7.
__global__ void k_pack(const float* __restrict__ W1, const float* __restrict__ W2,
                       ushort_t* __restrict__ Bp1, ushort_t* __restrict__ Bp2) {
    int tid = blockIdx.x * 256 + threadIdx.x;
    int id = (tid < 8192) ? tid : tid - 8192;
    int j = id & 7, lane = (id >> 3) & 63, t = (id >> 9) & 3, s = id >> 11;
    int k = s * 32 + ((lane >> 4) << 3) + j;
    int n = t * 16 + (lane & 15);
    if (tid < 8192)        Bp1[id] = f2bf(W1[k * 64 + n]);        // K=128: s in 0..3
    else if (tid < 12288)  Bp2[id] = f2bf(W2[k * 64 + n]);        // K=64 : s in 0..1
}

// ---------------- MFMA GEMM: out[N,64] = bf16((A[N,K] @ W) * dinv[row]) ----------------
template<int K, typename AT>
__global__ __launch_bounds__(256) void k_gemm_mfma(const AT* __restrict__ A,
        const ushort_t* __restrict__ Bp, const float* __restrict__ dinv,
        ushort_t* __restrict__ out, int N) {
    int wave = threadIdx.x >> 6, lane = threadIdx.x & 63;
    int m = lane & 15, q = lane >> 4;
    int row0 = blockIdx.x * 64 + wave * 16;
    int arow = row0 + m;
    int arowc = (arow < N) ? arow : (N - 1);
    f32x4 acc[4] = {};
    #pragma unroll
    for (int s = 0; s < K / 32; ++s) {
        bf16x8 af;
        if constexpr (sizeof(AT) == 4) {
            const float* ap = (const float*)A + (size_t)arowc * K + s * 32 + q * 8;
            float4 x0 = *(const float4*)ap;
            float4 x1 = *(const float4*)(ap + 4);
            af[0] = (short)f2bf(x0.x); af[1] = (short)f2bf(x0.y);
            af[2] = (short)f2bf(x0.z); af[3] = (short)f2bf(x0.w);
            af[4] = (short)f2bf(x1.x); af[5] = (short)f2bf(x1.y);
            af[6] = (short)f2bf(x1.z); af[7] = (short)f2bf(x1.w);
        } else {
            af = *(const bf16x8*)((const ushort_t*)A + (size_t)arowc * K + s * 32 + q * 8);
        }
        #pragma unroll
        for (int t = 0; t < 4; ++t) {
            bf16x8 bf = *(const bf16x8*)(Bp + (size_t)((s * 4 + t) * 64 + lane) * 8);
            acc[t] = __builtin_amdgcn_mfma_f32_16x16x32_bf16(af, bf, acc[t], 0, 0, 0);
        }
    }
    // C/D layout: col = lane&15, row = q*4 + r  [m89-verified]
    int orow0 = row0 + q * 4;
    float4 d4 = *(const float4*)(dinv + orow0);   // ws slack makes OOB read safe
    #pragma unroll
    for (int r = 0; r < 4; ++r) {
        int row = orow0 + r;
        if (row < N) {
            float dn = (r == 0) ? d4.x : (r == 1) ? d4.y : (r == 2) ? d4.z : d4.w;
            #pragma unroll
            for (int t = 0; t < 4; ++t)
                out[(size_t)row * 64 + t * 16 + m] = f2bf(acc[t][r] * dn);
        }
    }
}

// ---------------- pull aggregation: 8 lanes/node, 8 nodes/wave ----------------
// lane i of a group covers features i*8..i*8+7 (u16x8 = 16B loads). One gather
// instruction touches 8 independent random 128B lines; unroll 8 -> 64 lines
// in flight per wave.
__global__ __launch_bounds__(256) void k_aggregate(const ushort_t* __restrict__ xws,
        const int* __restrict__ rowptr, const int* __restrict__ col,
        const float* __restrict__ dinv, const float* __restrict__ bias,
        float* __restrict__ outf, ushort_t* __restrict__ outb, int N, int relu_bf16) {
    int n = (blockIdx.x * 256 + threadIdx.x) >> 3;
    int i = threadIdx.x & 7;
    if (n >= N) return;
    int beg = rowptr[n], end = rowptr[n + 1];
    float dn = dinv[n];
    const ushort_t* base = xws + i * 8;
    u16x8 sv = *(const u16x8*)(base + (size_t)n * 64);
    float a[8];
    #pragma unroll
    for (int k = 0; k < 8; ++k) a[k] = bf2f(sv[k]);   // self-loop term
    int e = beg;
    for (; e + 8 <= end; e += 8) {
        int c[8];
        #pragma unroll
        for (int j = 0; j < 8; ++j) c[j] = col[e + j];
        u16x8 v[8];
        #pragma unroll
        for (int j = 0; j < 8; ++j) v[j] = *(const u16x8*)(base + (size_t)c[j] * 64);
        #pragma unroll
        for (int j = 0; j < 8; ++j)
            #pragma unroll
            for (int k = 0; k < 8; ++k) a[k] += bf2f(v[j][k]);
    }
    if (e + 4 <= end) {
        int c[4];
        #pragma unroll
        for (int j = 0; j < 4; ++j) c[j] = col[e + j];
        u16x8 v[4];
        #pragma unroll
        for (int j = 0; j < 4; ++j) v[j] = *(const u16x8*)(base + (size_t)c[j] * 64);
        #pragma unroll
        for (int j = 0; j < 4; ++j)
            #pragma unroll
            for (int k = 0; k < 8; ++k) a[k] += bf2f(v[j][k]);
        e += 4;
    }
    for (; e < end; ++e) {
        u16x8 v = *(const u16x8*)(base + (size_t)col[e] * 64);
        #pragma unroll
        for (int k = 0; k < 8; ++k) a[k] += bf2f(v[k]);
    }
    float4 b0 = *(const float4*)(bias + i * 8);
    float4 b1 = *(const float4*)(bias + i * 8 + 4);
    float r[8];
    r[0] = dn * a[0] + b0.x; r[1] = dn * a[1] + b0.y;
    r[2] = dn * a[2] + b0.z; r[3] = dn * a[3] + b0.w;
    r[4] = dn * a[4] + b1.x; r[5] = dn * a[5] + b1.y;
    r[6] = dn * a[6] + b1.z; r[7] = dn * a[7] + b1.w;
    if (relu_bf16) {
        u16x8 o;
        #pragma unroll
        for (int k = 0; k < 8; ++k) o[k] = f2bf(fmaxf(r[k], 0.f));
        *(u16x8*)(outb + (size_t)n * 64 + i * 8) = o;
    } else {
        float4 o0 = {r[0], r[1], r[2], r[3]};
        float4 o1 = {r[4], r[5], r[6], r[7]};
        *(float4*)(outf + (size_t)n * 64 + i * 8) = o0;
        *(float4*)(outf + (size_t)n * 64 + i * 8 + 4) = o1;
    }
}

// ---------------- launch ----------------

extern "C" void kernel_launch(void* const* d_in, const int* in_sizes, int n_in,
                              void* d_out, int out_size, void* d_ws, size_t ws_size,
                              hipStream_t stream) {
    const float* x  = (const float*)d_in[0];
    const int*   ei = (const int*)d_in[1];
    const float* W1 = (const float*)d_in[2];
    const float* b1 = (const float*)d_in[3];
    const float* W2 = (const float*)d_in[4];
    const float* b2 = (const float*)d_in[5];
    float* out = (float*)d_out;

    const int N = in_sizes[0] / IN_F;
    const int E = in_sizes[1] / 2;
    const int* src = ei;        // edge_index[0]
    const int* dst = ei + E;    // edge_index[1]

    char* ws = (char*)d_ws;
    const size_t MB = 1u << 20;
    int*      bbase   = (int*)     (ws + 4096);              // 257 ints
    int*      gbase   = (int*)     (ws + 8192);              // 256 ints
    ushort_t* Bp1     = (ushort_t*)(ws + 16384);             // 8192 bf16 (16 KB)
    ushort_t* Bp2     = (ushort_t*)(ws + 49152);             // 4096 bf16 (8 KB)
    int*      rowptr  = (int*)     (ws + 1 * MB);            // N+1 ints
    float*    dinv    = (float*)   (ws + 2 * MB);            // N floats (+slack)
    unsigned* gbin    = (unsigned*)(ws + 3 * MB);            // E uints (6.4 MB)
    int*      ghist   = (int*)     (ws + 10 * MB);           // nbE*256 ints (~400 KB)
    int*      col     = (int*)     (ws + 11 * MB);           // E ints  (6.4 MB)
    ushort_t* xws     = (ushort_t*)(ws + 20 * MB);           // N*64 bf16 (12.8 MB)
    ushort_t* h       = (ushort_t*)(ws + 36 * MB);           // N*64 bf16 (12.8 MB)

    const int nbE = (E + CHUNK - 1) / CHUNK;                 // 391
    const int nbB = (N + BKT_SIZE - 1) / BKT_SIZE;           // 196 buckets (<= 256)
    const int nbG = (N + 63) / 64;                           // GEMM blocks
    const int nbA = (N * 8 + 255) / 256;                     // aggregate blocks

    k_pack    <<<48, 256, 0, stream>>>(W1, W2, Bp1, Bp2);
    k_hist    <<<nbE, 256, 0, stream>>>(dst, ghist, E);
    k_scanhist<<<1, 256, 0, stream>>>(ghist, gbase, bbase, rowptr, nbE, N, E);
    k_scatter <<<nbE, 256, 0, stream>>>(src, dst, ghist, gbase, gbin, E);
    k_fill2   <<<nbB, 256, 0, stream>>>(gbin, bbase, rowptr, dinv, col, N);

    // layer 1: xws = bf16((x @ W1) * dinv) ; h = bf16(relu(dinv*(sum+self) + b1))
    k_gemm_mfma<IN_F, float>   <<<nbG, 256, 0, stream>>>(x, Bp1, dinv, xws, N);
    k_aggregate<<<nbA, 256, 0, stream>>>(xws, rowptr, col, dinv, b1, nullptr, h, N, 1);

    // layer 2: xws = bf16((h @ W2) * dinv) ; out = dinv*(sum+self) + b2  (fp32)
    k_gemm_mfma<HID_F, ushort_t><<<nbG, 256, 0, stream>>>(h, Bp2, dinv, xws, N);
    k_aggregate<<<nbA, 256, 0, stream>>>(xws, rowptr, col, dinv, b2, out, nullptr, N, 0);
}

// Round 7
// 234.314 us; speedup vs baseline: 1.3848x; 1.3848x over previous
//
#include <hip/hip_runtime.h>

#define IN_F 128
#define HID_F 64
#define BKT_SHIFT 9            // 512 nodes per bucket
#define BKT_SIZE 512
#define CHUNK 4096             // edges per block in binning kernels

typedef unsigned short ushort_t;
typedef __attribute__((ext_vector_type(8))) short bf16x8;
typedef __attribute__((ext_vector_type(8))) unsigned short u16x8;
typedef __attribute__((ext_vector_type(4))) float f32x4;

__device__ inline ushort_t f2bf(float f) {     // RNE fp32 -> bf16 bits
    unsigned u = __float_as_uint(f);
    u += 0x7FFFu + ((u >> 16) & 1u);
    return (ushort_t)(u >> 16);
}
__device__ inline float bf2f(ushort_t u) {
    return __uint_as_float((unsigned)u << 16);
}

// ---------------- CSR build: atomic-free 2-level bucket sort by dst ----------------
// pack: (dst & 511) << 23 | src   (needs src < 2^23, nodes/bucket <= 512)

// per-block LDS histogram -> ghist[block][bucket]  (no global atomics)
__global__ __launch_bounds__(256) void k_hist(const int* __restrict__ dst,
        int* __restrict__ ghist, int E) {
    __shared__ int hist[256];
    int tid = threadIdx.x;
    hist[tid] = 0;
    __syncthreads();
    int e0 = blockIdx.x * CHUNK, e1 = min(e0 + CHUNK, E);
    for (int e = e0 + tid; e < e1; e += 256)
        atomicAdd(&hist[dst[e] >> BKT_SHIFT], 1);
    __syncthreads();
    ghist[blockIdx.x * 256 + tid] = hist[tid];
}

// 256 blocks, one per bucket: parallel exclusive scan over the nb per-block
// counts of this bucket (2 elements/thread, nb <= 512). totals -> gcount.
__global__ __launch_bounds__(256) void k_colscan(int* __restrict__ ghist,
        int* __restrict__ gcount, int nb) {
    __shared__ int s[256];
    int t = threadIdx.x;
    int b = blockIdx.x;
    int j0 = 2 * t, j1 = 2 * t + 1;
    int v0 = (j0 < nb) ? ghist[j0 * 256 + b] : 0;
    int v1 = (j1 < nb) ? ghist[j1 * 256 + b] : 0;
    int p = v0 + v1;
    s[t] = p;
    __syncthreads();
    for (int off = 1; off < 256; off <<= 1) {
        int v = (t >= off) ? s[t - off] : 0;
        __syncthreads();
        s[t] += v;
        __syncthreads();
    }
    int excl = s[t] - p;
    if (j0 < nb) ghist[j0 * 256 + b] = excl;
    if (j1 < nb) ghist[j1 * 256 + b] = excl + v0;
    if (t == 255) gcount[b] = s[255];
}

// single block: exclusive scan of 256 bucket totals -> gbase/bbase; rowptr[N]=E
__global__ __launch_bounds__(256) void k_bscan(const int* __restrict__ gcount,
        int* __restrict__ gbase, int* __restrict__ bbase,
        int* __restrict__ rowptr, int N, int E) {
    __shared__ int s[256];
    int t = threadIdx.x;
    int c = gcount[t];
    s[t] = c;
    __syncthreads();
    for (int off = 1; off < 256; off <<= 1) {
        int v = (t >= off) ? s[t - off] : 0;
        __syncthreads();
        s[t] += v;
        __syncthreads();
    }
    int base = s[t] - c;
    gbase[t] = base;
    bbase[t] = base;
    if (t == 255) bbase[256] = s[255];   // == E
    if (t == 0) rowptr[N] = E;
}

// scatter into bucket-contiguous gbin; cursors seeded from table, LDS atomics only
__global__ __launch_bounds__(256) void k_scatter(const int* __restrict__ src,
        const int* __restrict__ dst, const int* __restrict__ ghist,
        const int* __restrict__ gbase, unsigned* __restrict__ gbin, int E) {
    __shared__ int cur[256];
    int tid = threadIdx.x;
    cur[tid] = ghist[blockIdx.x * 256 + tid] + gbase[tid];
    __syncthreads();
    int e0 = blockIdx.x * CHUNK, e1 = min(e0 + CHUNK, E);
    for (int e = e0 + tid; e < e1; e += 256) {
        int d = dst[e];
        int b = d >> BKT_SHIFT;
        int p = atomicAdd(&cur[b], 1);
        gbin[p] = ((unsigned)(d & (BKT_SIZE - 1)) << 23) | (unsigned)src[e];
    }
}

// one block per bucket: per-node count (LDS), LDS scan of 512, write rowptr/dinv
// coalesced, then scatter col within the bucket's hot window via LDS cursors.
__global__ __launch_bounds__(256) void k_fill2(const unsigned* __restrict__ gbin,
        const int* __restrict__ bbase, int* __restrict__ rowptr,
        float* __restrict__ dinv, int* __restrict__ col, int N) {
    __shared__ int cnt[BKT_SIZE];
    __shared__ int pos[BKT_SIZE];
    __shared__ int s[256];
    int tid = threadIdx.x;
    int b = blockIdx.x;
    int e0 = bbase[b], e1 = bbase[b + 1];
    cnt[tid] = 0; cnt[tid + 256] = 0;
    __syncthreads();
    for (int e = e0 + tid; e < e1; e += 256)
        atomicAdd(&cnt[gbin[e] >> 23], 1);
    __syncthreads();
    int c0 = cnt[2 * tid], c1 = cnt[2 * tid + 1];
    int p2 = c0 + c1;
    s[tid] = p2;
    __syncthreads();
    for (int off = 1; off < 256; off <<= 1) {
        int v = (tid >= off) ? s[tid - off] : 0;
        __syncthreads();
        s[tid] += v;
        __syncthreads();
    }
    int excl = s[tid] - p2;
    pos[2 * tid] = excl;
    pos[2 * tid + 1] = excl + c0;
    __syncthreads();
    int n0 = b << BKT_SHIFT;
    #pragma unroll
    for (int i = tid; i < BKT_SIZE; i += 256) {
        int n = n0 + i;
        if (n < N) {
            rowptr[n] = e0 + pos[i];
            dinv[n] = rsqrtf((float)cnt[i] + 1.0f);   // +1 self-loop
        }
    }
    __syncthreads();
    for (int e = e0 + tid; e < e1; e += 256) {
        unsigned v = gbin[e];
        int p = atomicAdd(&pos[v >> 23], 1);
        col[e0 + p] = (int)(v & 0x7FFFFFu);
    }
}

// ---------------- W pre-pack into MFMA B-fragment order (bf16) ----------------
// B-frag (16x16x32): lane holds B[k = (lane>>4)*8 + j][n = lane&15], j=0..7.
__global__ void k_pack(const float* __restrict__ W1, const float* __restrict__ W2,
                       ushort_t* __restrict__ Bp1, ushort_t* __restrict__ Bp2) {
    int tid = blockIdx.x * 256 + threadIdx.x;
    int id = (tid < 8192) ? tid : tid - 8192;
    int j = id & 7, lane = (id >> 3) & 63, t = (id >> 9) & 3, s = id >> 11;
    int k = s * 32 + ((lane >> 4) << 3) + j;
    int n = t * 16 + (lane & 15);
    if (tid < 8192)        Bp1[id] = f2bf(W1[k * 64 + n]);        // K=128: s in 0..3
    else if (tid < 12288)  Bp2[id] = f2bf(W2[k * 64 + n]);        // K=64 : s in 0..1
}

// ---------------- MFMA GEMM: out[N,64] = bf16((A[N,K] @ W) * dinv[row]) ----------------
template<int K, typename AT>
__global__ __launch_bounds__(256) void k_gemm_mfma(const AT* __restrict__ A,
        const ushort_t* __restrict__ Bp, const float* __restrict__ dinv,
        ushort_t* __restrict__ out, int N) {
    int wave = threadIdx.x >> 6, lane = threadIdx.x & 63;
    int m = lane & 15, q = lane >> 4;
    int row0 = blockIdx.x * 64 + wave * 16;
    int arow = row0 + m;
    int arowc = (arow < N) ? arow : (N - 1);
    f32x4 acc[4] = {};
    #pragma unroll
    for (int s = 0; s < K / 32; ++s) {
        bf16x8 af;
        if constexpr (sizeof(AT) == 4) {
            const float* ap = (const float*)A + (size_t)arowc * K + s * 32 + q * 8;
            float4 x0 = *(const float4*)ap;
            float4 x1 = *(const float4*)(ap + 4);
            af[0] = (short)f2bf(x0.x); af[1] = (short)f2bf(x0.y);
            af[2] = (short)f2bf(x0.z); af[3] = (short)f2bf(x0.w);
            af[4] = (short)f2bf(x1.x); af[5] = (short)f2bf(x1.y);
            af[6] = (short)f2bf(x1.z); af[7] = (short)f2bf(x1.w);
        } else {
            af = *(const bf16x8*)((const ushort_t*)A + (size_t)arowc * K + s * 32 + q * 8);
        }
        #pragma unroll
        for (int t = 0; t < 4; ++t) {
            bf16x8 bf = *(const bf16x8*)(Bp + (size_t)((s * 4 + t) * 64 + lane) * 8);
            acc[t] = __builtin_amdgcn_mfma_f32_16x16x32_bf16(af, bf, acc[t], 0, 0, 0);
        }
    }
    // C/D layout: col = lane&15, row = q*4 + r  [m89-verified]
    int orow0 = row0 + q * 4;
    float4 d4 = *(const float4*)(dinv + orow0);   // ws slack makes OOB read safe
    #pragma unroll
    for (int r = 0; r < 4; ++r) {
        int row = orow0 + r;
        if (row < N) {
            float dn = (r == 0) ? d4.x : (r == 1) ? d4.y : (r == 2) ? d4.z : d4.w;
            #pragma unroll
            for (int t = 0; t < 4; ++t)
                out[(size_t)row * 64 + t * 16 + m] = f2bf(acc[t][r] * dn);
        }
    }
}

// ---------------- pull aggregation: 8 lanes/node, 8 nodes/wave ----------------
// lane i of a group covers features i*8..i*8+7 (u16x8 = 16B loads). One gather
// instruction touches 8 independent random 128B lines; unroll 8 -> 64 lines
// in flight per wave.
__global__ __launch_bounds__(256) void k_aggregate(const ushort_t* __restrict__ xws,
        const int* __restrict__ rowptr, const int* __restrict__ col,
        const float* __restrict__ dinv, const float* __restrict__ bias,
        float* __restrict__ outf, ushort_t* __restrict__ outb, int N, int relu_bf16) {
    int n = (blockIdx.x * 256 + threadIdx.x) >> 3;
    int i = threadIdx.x & 7;
    if (n >= N) return;
    int beg = rowptr[n], end = rowptr[n + 1];
    float dn = dinv[n];
    const ushort_t* base = xws + i * 8;
    u16x8 sv = *(const u16x8*)(base + (size_t)n * 64);
    float a[8];
    #pragma unroll
    for (int k = 0; k < 8; ++k) a[k] = bf2f(sv[k]);   // self-loop term
    int e = beg;
    for (; e + 8 <= end; e += 8) {
        int c[8];
        #pragma unroll
        for (int j = 0; j < 8; ++j) c[j] = col[e + j];
        u16x8 v[8];
        #pragma unroll
        for (int j = 0; j < 8; ++j) v[j] = *(const u16x8*)(base + (size_t)c[j] * 64);
        #pragma unroll
        for (int j = 0; j < 8; ++j)
            #pragma unroll
            for (int k = 0; k < 8; ++k) a[k] += bf2f(v[j][k]);
    }
    if (e + 4 <= end) {
        int c[4];
        #pragma unroll
        for (int j = 0; j < 4; ++j) c[j] = col[e + j];
        u16x8 v[4];
        #pragma unroll
        for (int j = 0; j < 4; ++j) v[j] = *(const u16x8*)(base + (size_t)c[j] * 64);
        #pragma unroll
        for (int j = 0; j < 4; ++j)
            #pragma unroll
            for (int k = 0; k < 8; ++k) a[k] += bf2f(v[j][k]);
        e += 4;
    }
    for (; e < end; ++e) {
        u16x8 v = *(const u16x8*)(base + (size_t)col[e] * 64);
        #pragma unroll
        for (int k = 0; k < 8; ++k) a[k] += bf2f(v[k]);
    }
    float4 b0 = *(const float4*)(bias + i * 8);
    float4 b1 = *(const float4*)(bias + i * 8 + 4);
    float r[8];
    r[0] = dn * a[0] + b0.x; r[1] = dn * a[1] + b0.y;
    r[2] = dn * a[2] + b0.z; r[3] = dn * a[3] + b0.w;
    r[4] = dn * a[4] + b1.x; r[5] = dn * a[5] + b1.y;
    r[6] = dn * a[6] + b1.z; r[7] = dn * a[7] + b1.w;
    if (relu_bf16) {
        u16x8 o;
        #pragma unroll
        for (int k = 0; k < 8; ++k) o[k] = f2bf(fmaxf(r[k], 0.f));
        *(u16x8*)(outb + (size_t)n * 64 + i * 8) = o;
    } else {
        float4 o0 = {r[0], r[1], r[2], r[3]};
        float4 o1 = {r[4], r[5], r[6], r[7]};
        *(float4*)(outf + (size_t)n * 64 + i * 8) = o0;
        *(float4*)(outf + (size_t)n * 64 + i * 8 + 4) = o1;
    }
}

// ---------------- launch ----------------

extern "C" void kernel_launch(void* const* d_in, const int* in_sizes, int n_in,
                              void* d_out, int out_size, void* d_ws, size_t ws_size,
                              hipStream_t stream) {
    const float* x  = (const float*)d_in[0];
    const int*   ei = (const int*)d_in[1];
    const float* W1 = (const float*)d_in[2];
    const float* b1 = (const float*)d_in[3];
    const float* W2 = (const float*)d_in[4];
    const float* b2 = (const float*)d_in[5];
    float* out = (float*)d_out;

    const int N = in_sizes[0] / IN_F;
    const int E = in_sizes[1] / 2;
    const int* src = ei;        // edge_index[0]
    const int* dst = ei + E;    // edge_index[1]

    char* ws = (char*)d_ws;
    const size_t MB = 1u << 20;
    int*      bbase   = (int*)     (ws + 4096);              // 257 ints
    int*      gbase   = (int*)     (ws + 8192);              // 256 ints
    int*      gcount  = (int*)     (ws + 12288);             // 256 ints
    ushort_t* Bp1     = (ushort_t*)(ws + 16384);             // 8192 bf16 (16 KB)
    ushort_t* Bp2     = (ushort_t*)(ws + 49152);             // 4096 bf16 (8 KB)
    int*      rowptr  = (int*)     (ws + 1 * MB);            // N+1 ints
    float*    dinv    = (float*)   (ws + 2 * MB);            // N floats (+slack)
    unsigned* gbin    = (unsigned*)(ws + 3 * MB);            // E uints (6.4 MB)
    int*      ghist   = (int*)     (ws + 10 * MB);           // nbE*256 ints (~400 KB)
    int*      col     = (int*)     (ws + 11 * MB);           // E ints  (6.4 MB)
    ushort_t* xws     = (ushort_t*)(ws + 20 * MB);           // N*64 bf16 (12.8 MB)
    ushort_t* h       = (ushort_t*)(ws + 36 * MB);           // N*64 bf16 (12.8 MB)

    const int nbE = (E + CHUNK - 1) / CHUNK;                 // 391 (<= 512 for colscan)
    const int nbB = (N + BKT_SIZE - 1) / BKT_SIZE;           // 196 buckets (<= 256)
    const int nbG = (N + 63) / 64;                           // GEMM blocks
    const int nbA = (N * 8 + 255) / 256;                     // aggregate blocks

    k_pack   <<<48, 256, 0, stream>>>(W1, W2, Bp1, Bp2);
    k_hist   <<<nbE, 256, 0, stream>>>(dst, ghist, E);
    k_colscan<<<256, 256, 0, stream>>>(ghist, gcount, nbE);
    k_bscan  <<<1, 256, 0, stream>>>(gcount, gbase, bbase, rowptr, N, E);
    k_scatter<<<nbE, 256, 0, stream>>>(src, dst, ghist, gbase, gbin, E);
    k_fill2  <<<nbB, 256, 0, stream>>>(gbin, bbase, rowptr, dinv, col, N);

    // layer 1: xws = bf16((x @ W1) * dinv) ; h = bf16(relu(dinv*(sum+self) + b1))
    k_gemm_mfma<IN_F, float>   <<<nbG, 256, 0, stream>>>(x, Bp1, dinv, xws, N);
    k_aggregate<<<nbA, 256, 0, stream>>>(xws, rowptr, col, dinv, b1, nullptr, h, N, 1);

    // layer 2: xws = bf16((h @ W2) * dinv) ; out = dinv*(sum+self) + b2  (fp32)
    k_gemm_mfma<HID_F, ushort_t><<<nbG, 256, 0, stream>>>(h, Bp2, dinv, xws, N);
    k_aggregate<<<nbA, 256, 0, stream>>>(xws, rowptr, col, dinv, b2, out, nullptr, N, 0);
}